// Round 1
// baseline (2364.630 us; speedup 1.0000x reference)
//
#include <hip/hip_runtime.h>
#include <cstdint>
#include <cstddef>

#define BB   64      // batch
#define TT   256     // time steps
#define EE   300     // embed dim
#define HH   512     // hidden
#define G4H  2048    // 4*H
#define NCLS 18
#define DFF  256

__device__ __forceinline__ float fast_exp2(float x) { return __builtin_amdgcn_exp2f(x); }
__device__ __forceinline__ float sigmoid_f(float x) {
  return 1.0f / (1.0f + fast_exp2(x * -1.442695040888963f));
}
__device__ __forceinline__ float tanh_f(float x) {
  return 2.0f / (1.0f + fast_exp2(x * -2.885390081777927f)) - 1.0f;
}

// ---------------------------------------------------------------------------
// Kernel A: embedding gather + input projection for a chunk of timesteps.
// Block = 256 threads (4 waves). blockIdx.x = tl*128 + rs; each block computes
// 16 gate-rows x 64 batch for one t. Wave w owns k-slice [76w, 76w+klen).
// Lane = batch element. W rows are wave-uniform -> s_load; x-slice in VGPRs.
// Writes xW[tl][row][b] = sum_k W_ih[tag][row][k]*x[b][k] + b_ih + b_hh.
// ---------------------------------------------------------------------------
__global__ __launch_bounds__(256) void xproj_kernel(
    const int* __restrict__ tokens, const int* __restrict__ tags,
    const float* __restrict__ emb, const float* __restrict__ W_ih,
    const float* __restrict__ b_ih, const float* __restrict__ b_hh,
    float* __restrict__ xW, int t0)
{
  const int tid  = threadIdx.x;
  const int lane = tid & 63;
  const int w    = tid >> 6;                  // wave 0..3
  const int rs   = blockIdx.x & 127;          // row-slice (16 rows each)
  const int tl   = blockIdx.x >> 7;           // t within chunk
  const int t    = t0 + tl;
  const int tag  = tags[t];
  const int row0 = rs * 16;
  const int kbeg = __builtin_amdgcn_readfirstlane(w * 76);
  const bool full = (w != 3);                 // waves 0..2: 76 k's, wave 3: 72

  // gather this lane's x-slice (contiguous within one emb row, 16B aligned)
  const int tok = tokens[lane * TT + t];
  const float* xrow = emb + (size_t)tok * EE + kbeg;
  float xr[76];
  #pragma unroll
  for (int i = 0; i < 18; ++i) {
    const float4 v = *reinterpret_cast<const float4*>(xrow + i * 4);
    xr[i*4+0] = v.x; xr[i*4+1] = v.y; xr[i*4+2] = v.z; xr[i*4+3] = v.w;
  }
  if (full) {
    const float4 v = *reinterpret_cast<const float4*>(xrow + 72);
    xr[72] = v.x; xr[73] = v.y; xr[74] = v.z; xr[75] = v.w;
  } else {
    xr[72] = 0.f; xr[73] = 0.f; xr[74] = 0.f; xr[75] = 0.f;
  }

  const float* Wbase = W_ih + (size_t)tag * ((size_t)G4H * EE);
  __shared__ float red[4][16][64];
  #pragma unroll
  for (int r = 0; r < 16; ++r) {
    const float* Wr = Wbase + (size_t)(row0 + r) * EE + kbeg;  // uniform -> s_load
    float a = 0.f;
    #pragma unroll
    for (int k = 0; k < 72; ++k) a = fmaf(Wr[k], xr[k], a);
    if (full) {
      #pragma unroll
      for (int k = 72; k < 76; ++k) a = fmaf(Wr[k], xr[k], a);
    }
    red[w][r][lane] = a;
  }
  __syncthreads();
  #pragma unroll
  for (int it = 0; it < 4; ++it) {
    const int item = tid + it * 256;          // 16*64 = 1024 items
    const int r = item >> 6, b = item & 63;
    const int row = row0 + r;
    float s = red[0][r][b] + red[1][r][b] + red[2][r][b] + red[3][r][b];
    s += b_ih[tag * G4H + row] + b_hh[tag * G4H + row];
    xW[((size_t)tl * G4H + row) * BB + b] = s;
  }
}

// ---------------------------------------------------------------------------
// Kernel B: one LSTM step. Grid 256 blocks x 1024 threads (16 waves).
// Block owns 2 hidden indices j0,j0+1 (8 gate rows). Wave w owns k-slice of 32.
// h layout [k][b] (k-major), ping-pong buffers. c persistent [j][b].
// ---------------------------------------------------------------------------
__global__ __launch_bounds__(1024) void step_kernel(
    const int* __restrict__ tags, const float* __restrict__ W_hh,
    const float* __restrict__ xW, const float* __restrict__ h_in,
    float* __restrict__ h_out, float* __restrict__ cst,
    int t, int tl)
{
  const int tid  = threadIdx.x;
  const int lane = tid & 63;
  const int w    = tid >> 6;                  // 0..15
  const int j0   = blockIdx.x * 2;
  const int tag  = tags[t];
  const int kbeg = __builtin_amdgcn_readfirstlane(w * 32);

  float xr[32];
  const float* hp = h_in + (size_t)kbeg * BB + lane;
  #pragma unroll
  for (int i = 0; i < 32; ++i) xr[i] = hp[i * BB];  // coalesced 256B per i

  const float* Wbase = W_hh + (size_t)tag * ((size_t)G4H * HH);
  __shared__ float red[16][8][64];
  #pragma unroll
  for (int g = 0; g < 4; ++g) {
    #pragma unroll
    for (int jj = 0; jj < 2; ++jj) {
      const int row = j0 + jj + g * HH;       // PyTorch gate order i,f,g,o
      const float* Wr = Wbase + (size_t)row * HH + kbeg;  // uniform -> s_load
      float a = 0.f;
      #pragma unroll
      for (int k = 0; k < 32; ++k) a = fmaf(Wr[k], xr[k], a);
      red[w][g * 2 + jj][lane] = a;
    }
  }
  __syncthreads();
  __shared__ float gate[8][64];
  if (tid < 512) {
    const int r = tid >> 6, b = tid & 63;
    const int row = j0 + (r & 1) + (r >> 1) * HH;
    float s = 0.f;
    #pragma unroll
    for (int ww = 0; ww < 16; ++ww) s += red[ww][r][b];
    s += xW[((size_t)tl * G4H + row) * BB + b];
    gate[r][b] = s;
  }
  __syncthreads();
  if (tid < 128) {
    const int jj = tid >> 6, b = tid & 63;
    const int j = j0 + jj;
    const float i_ = sigmoid_f(gate[0 + jj][b]);
    const float f_ = sigmoid_f(gate[2 + jj][b]);
    const float g_ = tanh_f   (gate[4 + jj][b]);
    const float o_ = sigmoid_f(gate[6 + jj][b]);
    const size_t idx = (size_t)j * BB + b;
    const float cv = f_ * cst[idx] + i_ * g_;
    cst[idx] = cv;
    h_out[idx] = o_ * tanh_f(cv);
  }
}

// ---------------------------------------------------------------------------
// Head 1: hid[d][b] = relu(b1[d] + sum_k W1[d][k] * h[k][b]).  Grid 32 x 1024.
// ---------------------------------------------------------------------------
__global__ __launch_bounds__(1024) void head1_kernel(
    const float* __restrict__ W1, const float* __restrict__ b1,
    const float* __restrict__ hfin, float* __restrict__ hid)
{
  const int tid  = threadIdx.x;
  const int lane = tid & 63;
  const int w    = tid >> 6;
  const int row0 = blockIdx.x * 8;
  const int kbeg = __builtin_amdgcn_readfirstlane(w * 32);
  float xr[32];
  const float* hp = hfin + (size_t)kbeg * BB + lane;
  #pragma unroll
  for (int i = 0; i < 32; ++i) xr[i] = hp[i * BB];
  __shared__ float red[16][8][64];
  #pragma unroll
  for (int r = 0; r < 8; ++r) {
    const float* Wr = W1 + (size_t)(row0 + r) * HH + kbeg;
    float a = 0.f;
    #pragma unroll
    for (int k = 0; k < 32; ++k) a = fmaf(Wr[k], xr[k], a);
    red[w][r][lane] = a;
  }
  __syncthreads();
  if (tid < 512) {
    const int r = tid >> 6, b = tid & 63;
    float s = 0.f;
    #pragma unroll
    for (int ww = 0; ww < 16; ++ww) s += red[ww][r][b];
    s += b1[row0 + r];
    hid[(size_t)(row0 + r) * BB + b] = fmaxf(s, 0.f);
  }
}

// ---------------------------------------------------------------------------
// Head 2: out[b][r] = b2[r] + sum_d W2[r][d] * hid[d][b].  1 block x 256.
// ---------------------------------------------------------------------------
__global__ __launch_bounds__(256) void head2_kernel(
    const float* __restrict__ W2, const float* __restrict__ b2,
    const float* __restrict__ hid, float* __restrict__ out)
{
  const int tid  = threadIdx.x;
  const int lane = tid & 63;
  const int w    = tid >> 6;                  // 0..3
  const int kbeg = __builtin_amdgcn_readfirstlane(w * 64);
  float xr[64];
  const float* hp = hid + (size_t)kbeg * BB + lane;
  #pragma unroll
  for (int i = 0; i < 64; ++i) xr[i] = hp[i * BB];
  __shared__ float red[4][NCLS][64];
  #pragma unroll
  for (int r = 0; r < NCLS; ++r) {
    const float* Wr = W2 + (size_t)r * DFF + kbeg;
    float a = 0.f;
    #pragma unroll
    for (int k = 0; k < 64; ++k) a = fmaf(Wr[k], xr[k], a);
    red[w][r][lane] = a;
  }
  __syncthreads();
  for (int it = 0; it < 5; ++it) {
    const int item = tid + it * 256;          // 18*64 = 1152 items
    if (item < NCLS * 64) {
      const int r = item >> 6, b = item & 63;
      float s = red[0][r][b] + red[1][r][b] + red[2][r][b] + red[3][r][b];
      out[(size_t)b * NCLS + r] = s + b2[r];
    }
  }
}

// ---------------------------------------------------------------------------
extern "C" void kernel_launch(void* const* d_in, const int* in_sizes, int n_in,
                              void* d_out, int out_size, void* d_ws, size_t ws_size,
                              hipStream_t stream)
{
  const int*   tokens = (const int*)  d_in[0];
  const int*   tags   = (const int*)  d_in[1];
  const float* emb    = (const float*)d_in[2];
  const float* W_ih   = (const float*)d_in[3];
  const float* W_hh   = (const float*)d_in[4];
  const float* b_ih   = (const float*)d_in[5];
  const float* b_hh   = (const float*)d_in[6];
  const float* W1     = (const float*)d_in[7];
  const float* b1     = (const float*)d_in[8];
  const float* W2     = (const float*)d_in[9];
  const float* b2     = (const float*)d_in[10];
  float* out = (float*)d_out;

  // ws layout: [xW chunk][hA][hB][c][hid]; chunk timesteps to fit ws_size.
  const size_t per_t = (size_t)G4H * BB * sizeof(float);   // 512 KB per timestep
  int TCH = 8;
  for (int c = 256; c >= 8; c >>= 1) {
    if ((size_t)c * per_t + (1u << 20) <= ws_size) { TCH = c; break; }
  }
  char* p = (char*)d_ws;
  float* xW  = (float*)p;  p += (size_t)TCH * per_t;
  float* hA  = (float*)p;  p += (size_t)HH * BB * sizeof(float);
  float* hB  = (float*)p;  p += (size_t)HH * BB * sizeof(float);
  float* cst = (float*)p;  p += (size_t)HH * BB * sizeof(float);
  float* hid = (float*)p;

  hipMemsetAsync(hA,  0, (size_t)HH * BB * sizeof(float), stream);   // h0 = 0
  hipMemsetAsync(cst, 0, (size_t)HH * BB * sizeof(float), stream);   // c0 = 0

  for (int c0 = 0; c0 < TT; c0 += TCH) {
    xproj_kernel<<<dim3((unsigned)TCH * 128), dim3(256), 0, stream>>>(
        tokens, tags, emb, W_ih, b_ih, b_hh, xW, c0);
    for (int t = c0; t < c0 + TCH; ++t) {
      const float* h_in  = (t & 1) ? hB : hA;
      float*       h_out = (t & 1) ? hA : hB;
      step_kernel<<<dim3(256), dim3(1024), 0, stream>>>(
          tags, W_hh, xW, h_in, h_out, cst, t, t - c0);
    }
  }
  // T=256 even -> final h in hA
  head1_kernel<<<dim3(32), dim3(1024), 0, stream>>>(W1, b1, hA, hid);
  head2_kernel<<<dim3(1), dim3(256), 0, stream>>>(W2, b2, hid, out);
}